// Round 1
// 478.379 us; speedup vs baseline: 1.0208x; 1.0208x over previous
//
#include <hip/hip_runtime.h>

// AdaptiveMask: out = (x * mask) / (sum(x * mask, axis=-1) + 1e-8)
// x: (262144 rows, 289) fp32. mask: per-row-constant 17x17 ring pattern.
//
// Round 3 (polish): pass-1 mask reads were 4x ds_read_b32 per lane at
// word-stride-4 across lanes -> 8 lanes/bank = 8-way LDS conflict (~2.9x,
// m136). Replaced with a 4x-replicated 1156-float LDS table indexed
// directly by float4 index i4 -> one conflict-free ds_read_b128 per
// iteration (20 conflicted reads -> 5 clean ones per lane). Reciprocal
// moved from fp64 divide to fp32 divide after rounding the fp64 sum
// (same result to ~1 ulp; much shorter chain on the wave's serial tail).
// Nontemporal hints on the streaming x load / out store (read-once /
// write-once; keep L2/L3 allocation pressure down). fp64 accumulators
// and butterfly reduction kept unchanged (tolerance-proven).

typedef float vf4 __attribute__((ext_vector_type(4)));

constexpr int L   = 8;
constexpr int K   = 2 * L + 1;     // 17
constexpr int KK  = K * K;         // 289
constexpr int RPG = 4;             // rows per wave-group
constexpr int GF  = KK * RPG;      // 1156 floats per group
constexpr int GF4 = GF / 4;        // 289 float4s per group
constexpr int WPB = 4;             // waves per block (256 threads)

__global__ __launch_bounds__(256) void adamask_kernel(
    const vf4* __restrict__ x,
    const float* __restrict__ cur_val,
    const float* __restrict__ tmpl,
    vf4* __restrict__ out,
    int ngroups, int max_size)
{
    // Replicated mask: smask[p] = mask2d[p % 289] for p in [0, 1156).
    // float4-indexable and 16B-aligned -> ds_read_b128, no bank conflicts.
    __shared__ __align__(16) float smask[GF];

    const int tid = threadIdx.x;

    {
        const float cv   = cur_val[0];
        const float bias = cv * (float)max_size;
        for (int p = tid; p < GF; p += 256) {
            const int rr = (p >= KK) + (p >= 2 * KK) + (p >= 3 * KK);
            const int q  = p - rr * KK;          // q = p % 289
            const int r  = q / K;                // const divisor -> magic mul
            const int c  = q - r * K;
            const int d  = max(abs(r - L), abs(c - L));
            float mv = 1.0f;
            if (d != 0) {
                const int j = min(max(L - d, 0), L - 1);
                const float od = (tmpl[max_size - L + j] + bias) * 0.125f + 1.0f;
                mv = fminf(fmaxf(od, 0.0f), 1.0f);
            }
            smask[p] = mv;
        }
    }
    __syncthreads();

    const int lane = tid & 63;
    const int wave = tid >> 6;
    const long long grp = (long long)blockIdx.x * WPB + wave;
    if (grp >= ngroups) return;   // wave-uniform

    const vf4* __restrict__ xg = x + grp * GF4;
    vf4* __restrict__ og       = out + grp * GF4;
    const vf4* __restrict__ m4 = reinterpret_cast<const vf4*>(smask);

    // Pass 1: load, mask, accumulate per-sub-row sums (fp64).
    vf4 v[5];
    double acc0 = 0.0, acc1 = 0.0, acc2 = 0.0, acc3 = 0.0;

#pragma unroll
    for (int k = 0; k < 5; ++k) {
        const int i4 = lane + 64 * k;
        if (i4 < GF4) {
            const vf4 xv = __builtin_nontemporal_load(&xg[i4]);
            const vf4 mv = m4[i4];               // ds_read_b128, conflict-free
            const vf4 val = xv * mv;
            const int pbase = 4 * i4;
#pragma unroll
            for (int j = 0; j < 4; ++j) {
                const int p = pbase + j;
                const int r = (p >= KK) + (p >= 2 * KK) + (p >= 3 * KK);
                const double dv = (double)val[j];
                if (r == 0)      acc0 += dv;
                else if (r == 1) acc1 += dv;
                else if (r == 2) acc2 += dv;
                else             acc3 += dv;
            }
            v[k] = val;
        } else {
            const vf4 z = {0.f, 0.f, 0.f, 0.f};
            v[k] = z;
        }
    }

    // 64-lane butterfly reductions (fp64) for the 4 sub-rows.
#pragma unroll
    for (int off = 32; off >= 1; off >>= 1) {
        acc0 += __shfl_xor(acc0, off, 64);
        acc1 += __shfl_xor(acc1, off, 64);
        acc2 += __shfl_xor(acc2, off, 64);
        acc3 += __shfl_xor(acc3, off, 64);
    }

    // fp32 reciprocal of the fp32-rounded fp64 sum (short div chain).
    const float i0 = 1.0f / ((float)acc0 + 1e-8f);
    const float i1 = 1.0f / ((float)acc1 + 1e-8f);
    const float i2 = 1.0f / ((float)acc2 + 1e-8f);
    const float i3 = 1.0f / ((float)acc3 + 1e-8f);

    // Pass 2: normalize from registers, vectorized nontemporal store.
#pragma unroll
    for (int k = 0; k < 5; ++k) {
        const int i4 = lane + 64 * k;
        if (i4 < GF4) {
            const vf4 val = v[k];
            const int pbase = 4 * i4;
            vf4 o;
#pragma unroll
            for (int j = 0; j < 4; ++j) {
                const int p = pbase + j;
                const int r = (p >= KK) + (p >= 2 * KK) + (p >= 3 * KK);
                const float iv = (r == 0) ? i0 : (r == 1) ? i1 : (r == 2) ? i2 : i3;
                o[j] = val[j] * iv;
            }
            __builtin_nontemporal_store(o, &og[i4]);
        }
    }
}

extern "C" void kernel_launch(void* const* d_in, const int* in_sizes, int n_in,
                              void* d_out, int out_size, void* d_ws, size_t ws_size,
                              hipStream_t stream)
{
    const float* x    = (const float*)d_in[0];
    const float* cv   = (const float*)d_in[1];
    const float* tmpl = (const float*)d_in[2];
    float* out = (float*)d_out;

    const int nrows    = in_sizes[0] / KK;   // 262144
    const int max_size = in_sizes[2];        // 32
    const int ngroups  = nrows / RPG;        // 65536 (nrows % 4 == 0)

    const int blocks = (ngroups + WPB - 1) / WPB;
    adamask_kernel<<<blocks, 64 * WPB, 0, stream>>>(
        (const vf4*)x, cv, tmpl, (vf4*)out, ngroups, max_size);
}